// Round 2
// baseline (515.793 us; speedup 1.0000x reference)
//
#include <hip/hip_runtime.h>
#include <cstdint>
#include <math.h>

#define BLOCK 256
#define SCAN_BLOCKS 2048
#define FINAL_BLOCKS 4096

__device__ __forceinline__ uint32_t f2key(float f) {
    uint32_t u = __float_as_uint(f);
    return (u & 0x80000000u) ? ~u : (u | 0x80000000u);
}
__device__ __forceinline__ float key2f(uint32_t k) {
    uint32_t u = (k & 0x80000000u) ? (k ^ 0x80000000u) : ~k;
    return __uint_as_float(u);
}

// ---- pass A: 4096-bin histogram of top 12 bits of sortable key ----
__global__ void histA_k(const float* __restrict__ t, int N, uint32_t* __restrict__ hist1) {
    __shared__ uint32_t h[4096];
    for (int i = threadIdx.x; i < 4096; i += BLOCK) h[i] = 0;
    __syncthreads();
    const float4* t4 = (const float4*)t;
    int n4 = N >> 2;
    int T = gridDim.x * BLOCK;
    int idx = blockIdx.x * BLOCK + threadIdx.x;
    int i = idx;
    for (; i + T < n4; i += 2 * T) {
        float4 a = t4[i];
        float4 b = t4[i + T];
        atomicAdd(&h[f2key(a.x) >> 20], 1u);
        atomicAdd(&h[f2key(a.y) >> 20], 1u);
        atomicAdd(&h[f2key(a.z) >> 20], 1u);
        atomicAdd(&h[f2key(a.w) >> 20], 1u);
        atomicAdd(&h[f2key(b.x) >> 20], 1u);
        atomicAdd(&h[f2key(b.y) >> 20], 1u);
        atomicAdd(&h[f2key(b.z) >> 20], 1u);
        atomicAdd(&h[f2key(b.w) >> 20], 1u);
    }
    for (; i < n4; i += T) {
        float4 a = t4[i];
        atomicAdd(&h[f2key(a.x) >> 20], 1u);
        atomicAdd(&h[f2key(a.y) >> 20], 1u);
        atomicAdd(&h[f2key(a.z) >> 20], 1u);
        atomicAdd(&h[f2key(a.w) >> 20], 1u);
    }
    if (blockIdx.x == 0 && threadIdx.x < (N & 3))
        atomicAdd(&h[f2key(t[(n4 << 2) + threadIdx.x]) >> 20], 1u);
    __syncthreads();
    for (int i2 = threadIdx.x; i2 < 4096; i2 += BLOCK) {
        uint32_t v = h[i2];
        if (v) atomicAdd(&hist1[i2], v);
    }
}

// ---- select over 4096 bins; one block per rank; computes its own rank from N ----
__global__ void select1_k(const uint32_t* __restrict__ hist1, int N,
                          uint32_t* __restrict__ b1, uint32_t* __restrict__ rem1) {
    int r = blockIdx.x;
    int j = (r >> 1) + 1;
    double pos = (double)(N - 1) * (double)j / 5.0;
    uint32_t rank = (uint32_t)pos + (r & 1);
    __shared__ uint32_t scan[BLOCK];
    uint32_t local[16];
    uint32_t s = 0;
    int t = threadIdx.x;
#pragma unroll
    for (int i = 0; i < 16; ++i) { local[i] = hist1[t * 16 + i]; s += local[i]; }
    scan[t] = s;
    __syncthreads();
    for (int off = 1; off < BLOCK; off <<= 1) {
        uint32_t v = (t >= off) ? scan[t - off] : 0u;
        __syncthreads();
        scan[t] += v;
        __syncthreads();
    }
    uint32_t cum = scan[t] - s;
#pragma unroll
    for (int i = 0; i < 16; ++i) {
        uint32_t c = local[i];
        if (rank >= cum && rank < cum + c) {
            b1[r] = (uint32_t)(t * 16 + i);
            rem1[r] = rank - cum;
        }
        cum += c;
    }
}

// ---- pass B: per-rank 2^20-bin GLOBAL histograms of low 20 bits (bucket members only) ----
__global__ void histB_k(const float* __restrict__ t, int N,
                        const uint32_t* __restrict__ b1, uint32_t* __restrict__ hist2) {
    uint32_t b[8];
#pragma unroll
    for (int r = 0; r < 8; ++r) b[r] = b1[r];
    const float4* t4 = (const float4*)t;
    int n4 = N >> 2;
    int T = gridDim.x * BLOCK;
    int idx = blockIdx.x * BLOCK + threadIdx.x;
    int i = idx;
    for (; i + T < n4; i += 2 * T) {
        float4 a = t4[i];
        float4 c4 = t4[i + T];
        float vals[8] = {a.x, a.y, a.z, a.w, c4.x, c4.y, c4.z, c4.w};
#pragma unroll
        for (int c = 0; c < 8; ++c) {
            uint32_t key = f2key(vals[c]);
            uint32_t top = key >> 20;
#pragma unroll
            for (int r = 0; r < 8; ++r)
                if (top == b[r]) atomicAdd(&hist2[((uint32_t)r << 20) | (key & 0xFFFFFu)], 1u);
        }
    }
    for (; i < n4; i += T) {
        float4 a = t4[i];
        float vals[4] = {a.x, a.y, a.z, a.w};
#pragma unroll
        for (int c = 0; c < 4; ++c) {
            uint32_t key = f2key(vals[c]);
            uint32_t top = key >> 20;
#pragma unroll
            for (int r = 0; r < 8; ++r)
                if (top == b[r]) atomicAdd(&hist2[((uint32_t)r << 20) | (key & 0xFFFFFu)], 1u);
        }
    }
    if (blockIdx.x == 0 && threadIdx.x < (N & 3)) {
        uint32_t key = f2key(t[(n4 << 2) + threadIdx.x]);
        uint32_t top = key >> 20;
        for (int r = 0; r < 8; ++r)
            if (top == b[r]) atomicAdd(&hist2[((uint32_t)r << 20) | (key & 0xFFFFFu)], 1u);
    }
}

// ---- select stage 1: per-rank per-16384-chunk partial sums (8 ranks x 64 chunks) ----
__global__ void selB1_k(const uint32_t* __restrict__ hist2, uint32_t* __restrict__ partial) {
    int r = blockIdx.x >> 6, c = blockIdx.x & 63;
    const uint32_t* h = hist2 + (((size_t)r << 20) | ((size_t)c << 14));
    uint32_t s = 0;
    for (int i = threadIdx.x; i < 16384; i += BLOCK) s += h[i];
    for (int off = 32; off > 0; off >>= 1) s += __shfl_down(s, off, 64);
    __shared__ uint32_t wsum[4];
    if ((threadIdx.x & 63) == 0) wsum[threadIdx.x >> 6] = s;
    __syncthreads();
    if (threadIdx.x == 0) partial[blockIdx.x] = wsum[0] + wsum[1] + wsum[2] + wsum[3];
}

// ---- select stage 2: locate chunk, then exact bin within chunk -> full 32-bit key ----
__global__ void selB2_k(const uint32_t* __restrict__ hist2,
                        const uint32_t* __restrict__ partial,
                        const uint32_t* __restrict__ b1,
                        const uint32_t* __restrict__ rem1,
                        uint32_t* __restrict__ keyout) {
    int r = blockIdx.x;
    __shared__ uint32_t sh_chunk, sh_rank;
    if (threadIdx.x == 0) {
        uint32_t rank = rem1[r];
        uint32_t cum = 0;
        uint32_t c = 0;
        for (; c < 64; ++c) {
            uint32_t v = partial[(r << 6) + c];
            if (rank < cum + v) break;
            cum += v;
        }
        sh_chunk = c;
        sh_rank = rank - cum;
    }
    __syncthreads();
    uint32_t chunk = sh_chunk, rank = sh_rank;
    const uint32_t* h = hist2 + (((size_t)r << 20) | ((size_t)chunk << 14));
    __shared__ uint32_t scan[BLOCK];
    uint32_t s = 0;
    int t = threadIdx.x;
    uint32_t local[64];
#pragma unroll
    for (int i = 0; i < 64; ++i) { local[i] = h[t * 64 + i]; s += local[i]; }
    scan[t] = s;
    __syncthreads();
    for (int off = 1; off < BLOCK; off <<= 1) {
        uint32_t v = (t >= off) ? scan[t - off] : 0u;
        __syncthreads();
        scan[t] += v;
        __syncthreads();
    }
    uint32_t cum = scan[t] - s;
#pragma unroll
    for (int i = 0; i < 64; ++i) {
        uint32_t c = local[i];
        if (rank >= cum && rank < cum + c)
            keyout[r] = (b1[r] << 20) | (chunk << 14) | (uint32_t)(t * 64 + i);
        cum += c;
    }
}

// ---- final: reconstruct quantiles, fused label+weight+MSE reduce ----
__global__ void final_k(const float* __restrict__ p, const float* __restrict__ t, int N,
                        const uint32_t* __restrict__ keyout, float* __restrict__ out) {
    float q1, q2, q3, q4;
    {
        float v[8];
#pragma unroll
        for (int r = 0; r < 8; ++r) v[r] = key2f(keyout[r]);
        float q[4];
#pragma unroll
        for (int j = 1; j <= 4; ++j) {
            double pos = (double)(N - 1) * (double)j / 5.0;
            double frac = pos - floor(pos);
            q[j - 1] = (float)((double)v[2 * (j - 1)] +
                               frac * ((double)v[2 * j - 1] - (double)v[2 * (j - 1)]));
        }
        q1 = q[0]; q2 = q[1]; q3 = q[2]; q4 = q[3];
    }
    int n4 = N >> 2;
    int T = gridDim.x * BLOCK;
    int idx = blockIdx.x * BLOCK + threadIdx.x;
    const float4* p4 = (const float4*)p;
    const float4* t4 = (const float4*)t;
    float acc = 0.f;
    int i = idx;
    for (; i + T < n4; i += 2 * T) {
        float4 pa = p4[i], ta = t4[i];
        float4 pb = p4[i + T], tb = t4[i + T];
        float pp[8] = {pa.x, pa.y, pa.z, pa.w, pb.x, pb.y, pb.z, pb.w};
        float tt[8] = {ta.x, ta.y, ta.z, ta.w, tb.x, tb.y, tb.z, tb.w};
#pragma unroll
        for (int c = 0; c < 8; ++c) {
            float tv = tt[c];
            int cls = (int)(tv > q1) + (int)(tv > q2) + (int)(tv > q3) + (int)(tv > q4);
            float w = fabsf(3.0f - (float)cls) * 0.33333334f;
            float d = pp[c] - tv;
            acc += w * d * d;
        }
    }
    for (; i < n4; i += T) {
        float4 pa = p4[i], ta = t4[i];
        float pp[4] = {pa.x, pa.y, pa.z, pa.w};
        float tt[4] = {ta.x, ta.y, ta.z, ta.w};
#pragma unroll
        for (int c = 0; c < 4; ++c) {
            float tv = tt[c];
            int cls = (int)(tv > q1) + (int)(tv > q2) + (int)(tv > q3) + (int)(tv > q4);
            float w = fabsf(3.0f - (float)cls) * 0.33333334f;
            float d = pp[c] - tv;
            acc += w * d * d;
        }
    }
    if (blockIdx.x == 0 && threadIdx.x < (N & 3)) {
        int ii = (n4 << 2) + threadIdx.x;
        float tv = t[ii];
        int cls = (int)(tv > q1) + (int)(tv > q2) + (int)(tv > q3) + (int)(tv > q4);
        float w = fabsf(3.0f - (float)cls) * 0.33333334f;
        float d = p[ii] - tv;
        acc += w * d * d;
    }
    for (int off = 32; off > 0; off >>= 1) acc += __shfl_down(acc, off, 64);
    __shared__ float wsum[BLOCK / 64];
    int lane = threadIdx.x & 63, wv = threadIdx.x >> 6;
    if (lane == 0) wsum[wv] = acc;
    __syncthreads();
    if (threadIdx.x == 0) {
        float s = 0.f;
#pragma unroll
        for (int i2 = 0; i2 < BLOCK / 64; ++i2) s += wsum[i2];
        float inv_n = (float)(1.0 / (double)N);
        atomicAdd(out, s * inv_n);
    }
}

extern "C" void kernel_launch(void* const* d_in, const int* in_sizes, int n_in,
                              void* d_out, int out_size, void* d_ws, size_t ws_size,
                              hipStream_t stream) {
    const float* pred = (const float*)d_in[0];
    const float* targ = (const float*)d_in[1];
    int N = in_sizes[1];
    uint32_t* ws = (uint32_t*)d_ws;
    uint32_t* hist1  = ws;            // 4096
    uint32_t* b1     = ws + 4096;     // 8
    uint32_t* rem1   = ws + 4104;     // 8
    uint32_t* keyout = ws + 4112;     // 8
    uint32_t* partial= ws + 4120;     // 512
    uint32_t* hist2  = ws + 8192;     // 8 * 2^20
    float* out = (float*)d_out;

    hipMemsetAsync(hist1, 0, 4096 * sizeof(uint32_t), stream);
    hipMemsetAsync(hist2, 0, (size_t)8 * (1u << 20) * sizeof(uint32_t), stream);
    hipMemsetAsync(d_out, 0, sizeof(float), stream);
    histA_k<<<SCAN_BLOCKS, BLOCK, 0, stream>>>(targ, N, hist1);
    select1_k<<<8, BLOCK, 0, stream>>>(hist1, N, b1, rem1);
    histB_k<<<SCAN_BLOCKS, BLOCK, 0, stream>>>(targ, N, b1, hist2);
    selB1_k<<<512, BLOCK, 0, stream>>>(hist2, partial);
    selB2_k<<<8, BLOCK, 0, stream>>>(hist2, partial, b1, rem1, keyout);
    final_k<<<FINAL_BLOCKS, BLOCK, 0, stream>>>(pred, targ, N, keyout, out);
}

// Round 3
// 339.896 us; speedup vs baseline: 1.5175x; 1.5175x over previous
//
#include <hip/hip_runtime.h>
#include <cstdint>
#include <math.h>

#define BLOCK 256
#define NBINS 8192          // top-13 bits of sortable key
#define HIST_BLOCKS 2048
#define FINAL_BLOCKS 4096

__device__ __forceinline__ uint32_t f2key(float f) {
    uint32_t u = __float_as_uint(f);
    return (u & 0x80000000u) ? ~u : (u | 0x80000000u);
}
__device__ __forceinline__ float key2f(uint32_t k) {
    uint32_t u = (k & 0x80000000u) ? (k ^ 0x80000000u) : ~k;
    return __uint_as_float(u);
}

// ---- pass 1: 8192-bin LDS histogram of top 13 bits of sortable key ----
__global__ void hist_k(const float* __restrict__ t, int N, uint32_t* __restrict__ hist) {
    __shared__ uint32_t h[NBINS];
    for (int i = threadIdx.x; i < NBINS; i += BLOCK) h[i] = 0;
    __syncthreads();
    const float4* t4 = (const float4*)t;
    int n4 = N >> 2;
    int T = gridDim.x * BLOCK;
    int i = blockIdx.x * BLOCK + threadIdx.x;
    for (; i + T < n4; i += 2 * T) {
        float4 a = t4[i];
        float4 b = t4[i + T];
        atomicAdd(&h[f2key(a.x) >> 19], 1u);
        atomicAdd(&h[f2key(a.y) >> 19], 1u);
        atomicAdd(&h[f2key(a.z) >> 19], 1u);
        atomicAdd(&h[f2key(a.w) >> 19], 1u);
        atomicAdd(&h[f2key(b.x) >> 19], 1u);
        atomicAdd(&h[f2key(b.y) >> 19], 1u);
        atomicAdd(&h[f2key(b.z) >> 19], 1u);
        atomicAdd(&h[f2key(b.w) >> 19], 1u);
    }
    for (; i < n4; i += T) {
        float4 a = t4[i];
        atomicAdd(&h[f2key(a.x) >> 19], 1u);
        atomicAdd(&h[f2key(a.y) >> 19], 1u);
        atomicAdd(&h[f2key(a.z) >> 19], 1u);
        atomicAdd(&h[f2key(a.w) >> 19], 1u);
    }
    if (blockIdx.x == 0 && threadIdx.x < (N & 3))
        atomicAdd(&h[f2key(t[(n4 << 2) + threadIdx.x]) >> 19], 1u);
    __syncthreads();
    for (int k = threadIdx.x; k < NBINS; k += BLOCK) {
        uint32_t v = h[k];
        if (v) atomicAdd(&hist[k], v);
    }
}

// ---- pass 2 (tiny, one block): interpolated quantiles from histogram ----
__global__ void quant_k(const uint32_t* __restrict__ hist, int N,
                        float* __restrict__ q, float* __restrict__ out) {
    constexpr int BPT = NBINS / BLOCK;  // 32
    __shared__ uint32_t scan[BLOCK];
    uint32_t local[BPT];
    uint32_t s = 0;
    int t = threadIdx.x;
#pragma unroll
    for (int i = 0; i < BPT; ++i) { local[i] = hist[t * BPT + i]; s += local[i]; }
    scan[t] = s;
    __syncthreads();
    for (int off = 1; off < BLOCK; off <<= 1) {
        uint32_t v = (t >= off) ? scan[t - off] : 0u;
        __syncthreads();
        scan[t] += v;
        __syncthreads();
    }
    uint32_t base = scan[t] - s;  // exclusive prefix for this thread's chunk
#pragma unroll 1
    for (int j = 0; j < 4; ++j) {
        double pos = (double)(N - 1) * (double)(j + 1) / 5.0;
        uint32_t cum = base;
#pragma unroll
        for (int i = 0; i < BPT; ++i) {
            uint32_t cnt = local[i];
            double cumd = (double)cum;
            if (pos >= cumd && pos < cumd + (double)cnt) {
                uint32_t bin = (uint32_t)(t * BPT + i);
                float vlo = key2f(bin << 19);
                float vhi = (bin == NBINS - 1) ? key2f(0xFFFFFFFFu)
                                               : key2f((bin + 1) << 19);
                double frac = (pos - cumd + 0.5) / (double)cnt;
                q[j] = (float)((double)vlo + frac * ((double)vhi - (double)vlo));
            }
            cum += cnt;
        }
    }
    if (t == 0) out[0] = 0.0f;  // init accumulator for final pass
}

// ---- pass 3: fused label+weight+MSE reduce over predictions & targets ----
__global__ void final_k(const float* __restrict__ p, const float* __restrict__ t, int N,
                        const float* __restrict__ qv, float* __restrict__ out) {
    float q1 = qv[0], q2 = qv[1], q3 = qv[2], q4 = qv[3];
    int n4 = N >> 2;
    int T = gridDim.x * BLOCK;
    const float4* p4 = (const float4*)p;
    const float4* t4 = (const float4*)t;
    float acc = 0.f;
    int i = blockIdx.x * BLOCK + threadIdx.x;
    for (; i + T < n4; i += 2 * T) {
        float4 pa = p4[i], ta = t4[i];
        float4 pb = p4[i + T], tb = t4[i + T];
        float pp[8] = {pa.x, pa.y, pa.z, pa.w, pb.x, pb.y, pb.z, pb.w};
        float tt[8] = {ta.x, ta.y, ta.z, ta.w, tb.x, tb.y, tb.z, tb.w};
#pragma unroll
        for (int c = 0; c < 8; ++c) {
            float tv = tt[c];
            int cls = (int)(tv > q1) + (int)(tv > q2) + (int)(tv > q3) + (int)(tv > q4);
            float w = fabsf(3.0f - (float)cls) * 0.33333334f;
            float d = pp[c] - tv;
            acc += w * d * d;
        }
    }
    for (; i < n4; i += T) {
        float4 pa = p4[i], ta = t4[i];
        float pp[4] = {pa.x, pa.y, pa.z, pa.w};
        float tt[4] = {ta.x, ta.y, ta.z, ta.w};
#pragma unroll
        for (int c = 0; c < 4; ++c) {
            float tv = tt[c];
            int cls = (int)(tv > q1) + (int)(tv > q2) + (int)(tv > q3) + (int)(tv > q4);
            float w = fabsf(3.0f - (float)cls) * 0.33333334f;
            float d = pp[c] - tv;
            acc += w * d * d;
        }
    }
    if (blockIdx.x == 0 && threadIdx.x < (N & 3)) {
        int ii = (n4 << 2) + threadIdx.x;
        float tv = t[ii];
        int cls = (int)(tv > q1) + (int)(tv > q2) + (int)(tv > q3) + (int)(tv > q4);
        float w = fabsf(3.0f - (float)cls) * 0.33333334f;
        float d = p[ii] - tv;
        acc += w * d * d;
    }
    for (int off = 32; off > 0; off >>= 1) acc += __shfl_down(acc, off, 64);
    __shared__ float wsum[BLOCK / 64];
    int lane = threadIdx.x & 63, wv = threadIdx.x >> 6;
    if (lane == 0) wsum[wv] = acc;
    __syncthreads();
    if (threadIdx.x == 0) {
        float ssum = 0.f;
#pragma unroll
        for (int k = 0; k < BLOCK / 64; ++k) ssum += wsum[k];
        float inv_n = (float)(1.0 / (double)N);
        atomicAdd(out, ssum * inv_n);
    }
}

extern "C" void kernel_launch(void* const* d_in, const int* in_sizes, int n_in,
                              void* d_out, int out_size, void* d_ws, size_t ws_size,
                              hipStream_t stream) {
    const float* pred = (const float*)d_in[0];
    const float* targ = (const float*)d_in[1];
    int N = in_sizes[1];
    uint32_t* ws = (uint32_t*)d_ws;
    uint32_t* hist = ws;              // NBINS
    float* qv = (float*)(ws + NBINS); // 4 floats
    float* out = (float*)d_out;

    hipMemsetAsync(hist, 0, NBINS * sizeof(uint32_t), stream);
    hist_k<<<HIST_BLOCKS, BLOCK, 0, stream>>>(targ, N, hist);
    quant_k<<<1, BLOCK, 0, stream>>>(hist, N, qv, out);
    final_k<<<FINAL_BLOCKS, BLOCK, 0, stream>>>(pred, targ, N, qv, out);
}